// Round 1
// baseline (10662.769 us; speedup 1.0000x reference)
//
#include <hip/hip_runtime.h>
#include <hip/hip_bf16.h>

// ---------------------------------------------------------------------------
// PointNet++ encoder (4 SA stages) for MI355X.
// Pipeline per stage: FPS -> gather new_xyz -> ball query -> fused group+MLP+maxpool.
// FPS / ball-query distance math uses fp contract(off) to match numpy per-op
// IEEE semantics (argmax selection must be exact; xyz output is raw copies).
// ---------------------------------------------------------------------------

#define B_SZ 4

// ------------------------------- FPS ---------------------------------------
// One block per batch. Points + running min-dist live in registers (strided
// assignment i = t + k*T). Per iteration: broadcast centroid via LDS, update
// dists, block-wide argmax with first-index tie-break (matches jnp.argmax).
template <int N, int NPOINT, int T>
__global__ __launch_bounds__(T) void fps_kernel(const float* __restrict__ xyz,
                                                int* __restrict__ fidx) {
#pragma clang fp contract(off)
  constexpr int PT = N / T;
  constexpr int NW = T / 64;
  const int b = blockIdx.x;
  const int t = threadIdx.x;
  const float* base = xyz + (size_t)b * N * 3;

  float px[PT], py[PT], pz[PT], dist[PT];
#pragma unroll
  for (int k = 0; k < PT; ++k) {
    int i = t + k * T;
    px[k] = base[i * 3 + 0];
    py[k] = base[i * 3 + 1];
    pz[k] = base[i * 3 + 2];
    dist[k] = 1e10f;
  }

  __shared__ float s_bv[NW];
  __shared__ int s_bi[NW];
  __shared__ float s_c[3];
  __shared__ int s_far;

  int far = 0;
  for (int it = 0; it < NPOINT; ++it) {
    if (t == 0) fidx[b * NPOINT + it] = far;
    if (t == (far & (T - 1))) {
      int k = far / T;
      s_c[0] = px[k];
      s_c[1] = py[k];
      s_c[2] = pz[k];
    }
    __syncthreads();
    float cx = s_c[0], cy = s_c[1], cz = s_c[2];

    float best = -1.0f;
    int bi = 0;
#pragma unroll
    for (int k = 0; k < PT; ++k) {
      float dx = px[k] - cx;
      float dy = py[k] - cy;
      float dz = pz[k] - cz;
      float d = dx * dx + dy * dy + dz * dz;  // contract(off): mul,add,add
      float nd = fminf(dist[k], d);
      dist[k] = nd;
      if (nd > best) {  // first occurrence kept -> smallest i for this thread
        best = nd;
        bi = t + k * T;
      }
    }
    // wave argmax (tie -> smaller index)
#pragma unroll
    for (int off = 32; off > 0; off >>= 1) {
      float ov = __shfl_xor(best, off);
      int oi = __shfl_xor(bi, off);
      if (ov > best || (ov == best && oi < bi)) {
        best = ov;
        bi = oi;
      }
    }
    int wv = t >> 6;
    if ((t & 63) == 0) {
      s_bv[wv] = best;
      s_bi[wv] = bi;
    }
    __syncthreads();
    if (t == 0) {
      float bb = s_bv[0];
      int ii = s_bi[0];
      for (int w = 1; w < NW; ++w) {
        float v = s_bv[w];
        int i2 = s_bi[w];
        if (v > bb || (v == bb && i2 < ii)) {
          bb = v;
          ii = i2;
        }
      }
      s_far = ii;
    }
    __syncthreads();
    far = s_far;
  }
}

// --------------------------- gather new_xyz --------------------------------
__global__ void gather_xyz_kernel(const float* __restrict__ xyz,
                                  const int* __restrict__ fidx,
                                  float* __restrict__ out, int N, int S) {
  int s = blockIdx.x * blockDim.x + threadIdx.x;
  int b = blockIdx.y;
  if (s < S) {
    int i = fidx[b * S + s];
    out[((size_t)(b * S + s)) * 3 + 0] = xyz[((size_t)(b * N + i)) * 3 + 0];
    out[((size_t)(b * S + s)) * 3 + 1] = xyz[((size_t)(b * N + i)) * 3 + 1];
    out[((size_t)(b * S + s)) * 3 + 2] = xyz[((size_t)(b * N + i)) * 3 + 2];
  }
}

// ----------------------------- ball query ----------------------------------
// One wave per query point. Scan N points in 64-chunks; ballot-ordered append
// of in-ball indices (ascending index = reference's sort semantics); pad with
// first neighbor. d2 formula replicates (|c|^2 + |x|^2) - 2*dot, contract off.
template <int N, int NS>
__global__ __launch_bounds__(256) void ball_query_kernel(
    const float* __restrict__ xyz, const float* __restrict__ new_xyz,
    int* __restrict__ nidx, int S, float r2) {
#pragma clang fp contract(off)
  const int wv = threadIdx.x >> 6;
  const int lane = threadIdx.x & 63;
  const int b = blockIdx.y;
  const int s = blockIdx.x * 4 + wv;
  __shared__ int s_idx[4][NS];
  const float* base = xyz + (size_t)b * N * 3;

  float cx = new_xyz[((size_t)(b * S + s)) * 3 + 0];
  float cy = new_xyz[((size_t)(b * S + s)) * 3 + 1];
  float cz = new_xyz[((size_t)(b * S + s)) * 3 + 2];
  float sc = (cx * cx + cy * cy) + cz * cz;

  int found = 0;
  for (int i0 = 0; i0 < N && found < NS; i0 += 64) {  // N % 64 == 0 always
    int i = i0 + lane;
    float x = base[i * 3 + 0];
    float y = base[i * 3 + 1];
    float z = base[i * 3 + 2];
    float sx = (x * x + y * y) + z * z;
    float dt = (cx * x + cy * y) + cz * z;
    float d2 = (sc + sx) - 2.0f * dt;
    bool inb = d2 < r2;
    unsigned long long m = __ballot(inb);
    if (inb) {
      int pos = found + __popcll(m & ((1ull << lane) - 1));
      if (pos < NS) s_idx[wv][pos] = i;
    }
    found += __popcll(m);
  }
  __syncthreads();
  int fcnt = found < NS ? found : NS;
  int first = s_idx[wv][0];
  int* outp = nidx + ((size_t)(b * S + s)) * NS;
  for (int j = lane; j < NS; j += 64) outp[j] = (j < fcnt) ? s_idx[wv][j] : first;
}

// --------------------------- fused group MLP -------------------------------
// act[R][CMAXP] in LDS holds activations in-place across the 3 layers.
// Thread grid RG x CG; each thread owns RPT rows x CPT cols; W streamed from
// L1/L2 (each W element feeds RPT=8 FMAs).
template <int R, int RG, int CG, int CMAXP, int CIN, int COUT>
__device__ __forceinline__ void mlp_layer(float* act, const float* __restrict__ w,
                                          const float* __restrict__ bias, int tid) {
  constexpr int RPT = R / RG;
  constexpr int CPT = COUT / CG;
  static_assert(RG * CG == 256, "thread grid");
  const int rg = tid / CG;
  const int cg = tid % CG;

  float acc[RPT][CPT];
#pragma unroll
  for (int rr = 0; rr < RPT; ++rr)
#pragma unroll
    for (int cc = 0; cc < CPT; ++cc) acc[rr][cc] = 0.f;

  constexpr int K4 = (CIN / 4) * 4;
  for (int k = 0; k < K4; k += 4) {
    float4 a[RPT];
#pragma unroll
    for (int rr = 0; rr < RPT; ++rr)
      a[rr] = *(const float4*)(&act[(rg * RPT + rr) * CMAXP + k]);
    float wvv[4][CPT];
#pragma unroll
    for (int kk = 0; kk < 4; ++kk)
#pragma unroll
      for (int cc = 0; cc < CPT; ++cc)
        wvv[kk][cc] = w[(size_t)(k + kk) * COUT + cg + cc * CG];
#pragma unroll
    for (int rr = 0; rr < RPT; ++rr) {
      float4 av = a[rr];
#pragma unroll
      for (int cc = 0; cc < CPT; ++cc) {
        acc[rr][cc] += av.x * wvv[0][cc];
        acc[rr][cc] += av.y * wvv[1][cc];
        acc[rr][cc] += av.z * wvv[2][cc];
        acc[rr][cc] += av.w * wvv[3][cc];
      }
    }
  }
#pragma unroll 1
  for (int k = K4; k < CIN; ++k) {
    float wvv[CPT];
#pragma unroll
    for (int cc = 0; cc < CPT; ++cc) wvv[cc] = w[(size_t)k * COUT + cg + cc * CG];
#pragma unroll
    for (int rr = 0; rr < RPT; ++rr) {
      float av = act[(rg * RPT + rr) * CMAXP + k];
#pragma unroll
      for (int cc = 0; cc < CPT; ++cc) acc[rr][cc] += av * wvv[cc];
    }
  }
  __syncthreads();  // all reads of act done before in-place overwrite
#pragma unroll
  for (int rr = 0; rr < RPT; ++rr)
#pragma unroll
    for (int cc = 0; cc < CPT; ++cc) {
      int co = cg + cc * CG;
      float v = acc[rr][cc] + bias[co];
      act[(rg * RPT + rr) * CMAXP + co] = fmaxf(v, 0.f);
    }
  __syncthreads();
}

template <int NS, int G, int CPREV, int CO0, int CO1, int CO2, int RG, int CG, int CMAXP>
__global__ __launch_bounds__(256) void group_mlp_kernel(
    const float* __restrict__ xyz, const float* __restrict__ new_xyz,
    const float* __restrict__ feats, const int* __restrict__ nidx,
    const float* __restrict__ w0, const float* __restrict__ b0,
    const float* __restrict__ w1, const float* __restrict__ b1,
    const float* __restrict__ w2, const float* __restrict__ b2,
    float* __restrict__ out, int N, int S, float radius) {
  constexpr int R = NS * G;
  constexpr int CIN = 3 + CPREV;
  __shared__ __align__(16) float act[R * CMAXP];
  const int tid = threadIdx.x;
  const int b = blockIdx.y;
  const int s0 = blockIdx.x * G;

  // stage inputs: rel xyz (exact sub + div by radius) and gathered feats
  for (int i = tid; i < R * CIN; i += 256) {
    int row = i / CIN;
    int ch = i - row * CIN;
    int g = row / NS;
    int j = row - g * NS;
    int sidx = s0 + g;
    int n = nidx[((size_t)(b * S + sidx)) * NS + j];
    float v;
    if constexpr (CPREV == 0) {
      v = (xyz[((size_t)(b * N + n)) * 3 + ch] -
           new_xyz[((size_t)(b * S + sidx)) * 3 + ch]) /
          radius;
    } else {
      if (ch < 3) {
        v = (xyz[((size_t)(b * N + n)) * 3 + ch] -
             new_xyz[((size_t)(b * S + sidx)) * 3 + ch]) /
            radius;
      } else {
        v = feats[((size_t)(b * N + n)) * CPREV + (ch - 3)];
      }
    }
    act[row * CMAXP + ch] = v;
  }
  __syncthreads();

  mlp_layer<R, RG, CG, CMAXP, CIN, CO0>(act, w0, b0, tid);
  mlp_layer<R, RG, CG, CMAXP, CO0, CO1>(act, w1, b1, tid);
  mlp_layer<R, RG, CG, CMAXP, CO1, CO2>(act, w2, b2, tid);

  // maxpool over NS neighbors per group
  for (int i = tid; i < G * CO2; i += 256) {
    int g = i / CO2;
    int co = i - g * CO2;
    float m = act[(g * NS) * CMAXP + co];
    for (int j = 1; j < NS; ++j) m = fmaxf(m, act[(g * NS + j) * CMAXP + co]);
    out[((size_t)(b * S + s0 + g)) * CO2 + co] = m;
  }
}

// ---------------------------------------------------------------------------
extern "C" void kernel_launch(void* const* d_in, const int* in_sizes, int n_in,
                              void* d_out, int out_size, void* d_ws, size_t ws_size,
                              hipStream_t stream) {
  (void)in_sizes; (void)n_in; (void)out_size; (void)ws_size;
  const float* pc = (const float*)d_in[0];
  const float* W[4][3];
  const float* Bb[4][3];
  for (int s = 0; s < 4; ++s)
    for (int l = 0; l < 3; ++l) {
      W[s][l] = (const float*)d_in[1 + s * 6 + l * 2];
      Bb[s][l] = (const float*)d_in[2 + s * 6 + l * 2];
    }

  // workspace layout (bytes): fidx 32KB | nidx 2MB | xyzA 96KB | xyzB 96KB |
  // featA 4MB | featB 4MB   (total ~10.2 MB)
  char* wsp = (char*)d_ws;
  int* fidx = (int*)wsp;
  int* nidx = (int*)(wsp + (32 << 10));
  float* xyzA = (float*)(wsp + (32 << 10) + (2 << 20));
  float* xyzB = xyzA + B_SZ * 2048 * 3;
  float* featA = xyzB + B_SZ * 2048 * 3;
  float* featB = featA + B_SZ * 2048 * 128;
  float* oxyz = (float*)d_out;           // [4,256,3]
  float* ofeat = oxyz + B_SZ * 256 * 3;  // [4,256,512]

  // ---------------- Stage 1: N=16384 -> S=2048, r=0.2, ns=64, 3->64->64->128
  hipLaunchKernelGGL((fps_kernel<16384, 2048, 1024>), dim3(B_SZ), dim3(1024), 0, stream,
                     pc, fidx);
  hipLaunchKernelGGL(gather_xyz_kernel, dim3(32, B_SZ), dim3(64), 0, stream,
                     pc, fidx, xyzA, 16384, 2048);
  hipLaunchKernelGGL((ball_query_kernel<16384, 64>), dim3(512, B_SZ), dim3(256), 0, stream,
                     pc, xyzA, nidx, 2048, (float)(0.2 * 0.2));
  hipLaunchKernelGGL((group_mlp_kernel<64, 1, 0, 64, 64, 128, 8, 32, 128>),
                     dim3(2048, B_SZ), dim3(256), 0, stream,
                     pc, xyzA, (const float*)nullptr, nidx,
                     W[0][0], Bb[0][0], W[0][1], Bb[0][1], W[0][2], Bb[0][2],
                     featA, 16384, 2048, 0.2f);

  // ---------------- Stage 2: N=2048 -> S=1024, r=0.4, ns=32, 131->128->128->256
  hipLaunchKernelGGL((fps_kernel<2048, 1024, 1024>), dim3(B_SZ), dim3(1024), 0, stream,
                     xyzA, fidx);
  hipLaunchKernelGGL(gather_xyz_kernel, dim3(16, B_SZ), dim3(64), 0, stream,
                     xyzA, fidx, xyzB, 2048, 1024);
  hipLaunchKernelGGL((ball_query_kernel<2048, 32>), dim3(256, B_SZ), dim3(256), 0, stream,
                     xyzA, xyzB, nidx, 1024, (float)(0.4 * 0.4));
  hipLaunchKernelGGL((group_mlp_kernel<32, 1, 128, 128, 128, 256, 4, 64, 256>),
                     dim3(1024, B_SZ), dim3(256), 0, stream,
                     xyzA, xyzB, featA, nidx,
                     W[1][0], Bb[1][0], W[1][1], Bb[1][1], W[1][2], Bb[1][2],
                     featB, 2048, 1024, 0.4f);

  // ---------------- Stage 3: N=1024 -> S=512, r=0.6, ns=16, 259->256->256->512
  hipLaunchKernelGGL((fps_kernel<1024, 512, 1024>), dim3(B_SZ), dim3(1024), 0, stream,
                     xyzB, fidx);
  hipLaunchKernelGGL(gather_xyz_kernel, dim3(8, B_SZ), dim3(64), 0, stream,
                     xyzB, fidx, xyzA, 1024, 512);
  hipLaunchKernelGGL((ball_query_kernel<1024, 16>), dim3(128, B_SZ), dim3(256), 0, stream,
                     xyzB, xyzA, nidx, 512, (float)(0.6 * 0.6));
  hipLaunchKernelGGL((group_mlp_kernel<16, 1, 256, 256, 256, 512, 2, 128, 512>),
                     dim3(512, B_SZ), dim3(256), 0, stream,
                     xyzB, xyzA, featB, nidx,
                     W[2][0], Bb[2][0], W[2][1], Bb[2][1], W[2][2], Bb[2][2],
                     featA, 1024, 512, 0.6f);

  // ---------------- Stage 4: N=512 -> S=256, r=1.2, ns=8, 515->512->512->512
  hipLaunchKernelGGL((fps_kernel<512, 256, 512>), dim3(B_SZ), dim3(512), 0, stream,
                     xyzA, fidx);
  hipLaunchKernelGGL(gather_xyz_kernel, dim3(4, B_SZ), dim3(64), 0, stream,
                     xyzA, fidx, oxyz, 512, 256);
  hipLaunchKernelGGL((ball_query_kernel<512, 8>), dim3(64, B_SZ), dim3(256), 0, stream,
                     xyzA, oxyz, nidx, 256, (float)(1.2 * 1.2));
  hipLaunchKernelGGL((group_mlp_kernel<8, 2, 512, 512, 512, 512, 2, 128, 516>),
                     dim3(128, B_SZ), dim3(256), 0, stream,
                     xyzA, oxyz, featA, nidx,
                     W[3][0], Bb[3][0], W[3][1], Bb[3][1], W[3][2], Bb[3][2],
                     ofeat, 512, 256, 1.2f);
}

// Round 2
// 5910.019 us; speedup vs baseline: 1.8042x; 1.8042x over previous
//
#include <hip/hip_runtime.h>
#include <hip/hip_bf16.h>

// ---------------------------------------------------------------------------
// PointNet++ encoder (4 SA stages) for MI355X.
// Pipeline per stage: FPS -> gather new_xyz -> ball query -> fused group+MLP+maxpool.
// FPS / ball-query distance math uses fp contract(off) to match numpy per-op
// IEEE semantics (argmax selection must be exact; xyz output is raw copies).
// ---------------------------------------------------------------------------

#define B_SZ 4

// ------------------------------- FPS ---------------------------------------
// One block per batch; ONE barrier per iteration.
// Packed u64 argmax: (float_bits(dist) << 32) | (N - idx)  -> max() == argmax
// with smallest-index tie-break (matches jnp.argmax first-occurrence).
// Wave leaders write packed best to double-buffered LDS; after one barrier all
// threads redundantly reduce the NW entries and compute `far` locally.
// Centroid: stages 2-4 read from a full LDS copy of xyz; stage 1 reads from
// global (L2-hit, one line for the whole block).
template <int N, int NPOINT, int T, bool XYZ_IN_LDS>
__global__ __launch_bounds__(T) void fps_kernel(const float* __restrict__ xyz,
                                                int* __restrict__ fidx) {
#pragma clang fp contract(off)
  constexpr int PT = N / T;
  constexpr int NW = T / 64;
  constexpr int LN = XYZ_IN_LDS ? N : 1;
  const int b = blockIdx.x;
  const int t = threadIdx.x;
  const int lane = t & 63;
  const int wv = t >> 6;
  const float* base = xyz + (size_t)b * N * 3;

  float px[PT], py[PT], pz[PT], dist[PT];
  __shared__ unsigned long long s_pack[2][NW];
  __shared__ float s_x[LN], s_y[LN], s_z[LN];

#pragma unroll
  for (int k = 0; k < PT; ++k) {
    int i = t + k * T;
    px[k] = base[i * 3 + 0];
    py[k] = base[i * 3 + 1];
    pz[k] = base[i * 3 + 2];
    dist[k] = 1e10f;
    if constexpr (XYZ_IN_LDS) {
      s_x[i] = px[k];
      s_y[i] = py[k];
      s_z[i] = pz[k];
    }
  }
  __syncthreads();

  int far = 0;
  int p = 0;
  for (int it = 0; it < NPOINT; ++it) {
    if (t == 0) fidx[b * NPOINT + it] = far;
    float cx, cy, cz;
    if constexpr (XYZ_IN_LDS) {
      cx = s_x[far];
      cy = s_y[far];
      cz = s_z[far];
    } else {
      cx = base[far * 3 + 0];
      cy = base[far * 3 + 1];
      cz = base[far * 3 + 2];
    }

    unsigned long long bestp = 0ull;
#pragma unroll
    for (int k = 0; k < PT; ++k) {
      float dx = px[k] - cx;
      float dy = py[k] - cy;
      float dz = pz[k] - cz;
      float d = dx * dx + dy * dy + dz * dz;  // contract(off): mul,add,add
      float nd = fminf(dist[k], d);
      dist[k] = nd;
      unsigned long long pk =
          ((unsigned long long)__float_as_uint(nd) << 32) |
          (unsigned int)(N - (t + k * T));
      bestp = pk > bestp ? pk : bestp;
    }
    // wave max-reduce on packed u64
#pragma unroll
    for (int off = 32; off > 0; off >>= 1) {
      unsigned long long o = __shfl_xor(bestp, off);
      bestp = o > bestp ? o : bestp;
    }
    if (lane == 0) s_pack[p][wv] = bestp;
    __syncthreads();
    unsigned long long bb = s_pack[p][0];
#pragma unroll
    for (int w = 1; w < NW; ++w) {
      unsigned long long v = s_pack[p][w];
      bb = v > bb ? v : bb;
    }
    far = N - (int)(unsigned int)(bb & 0xffffffffull);
    p ^= 1;
  }
}

// --------------------------- gather new_xyz --------------------------------
__global__ void gather_xyz_kernel(const float* __restrict__ xyz,
                                  const int* __restrict__ fidx,
                                  float* __restrict__ out, int N, int S) {
  int s = blockIdx.x * blockDim.x + threadIdx.x;
  int b = blockIdx.y;
  if (s < S) {
    int i = fidx[b * S + s];
    out[((size_t)(b * S + s)) * 3 + 0] = xyz[((size_t)(b * N + i)) * 3 + 0];
    out[((size_t)(b * S + s)) * 3 + 1] = xyz[((size_t)(b * N + i)) * 3 + 1];
    out[((size_t)(b * S + s)) * 3 + 2] = xyz[((size_t)(b * N + i)) * 3 + 2];
  }
}

// ----------------------------- ball query ----------------------------------
// One wave per query point. Scan N points in 64-chunks; ballot-ordered append
// of in-ball indices (ascending index = reference's sort semantics); pad with
// first neighbor. d2 formula replicates (|c|^2 + |x|^2) - 2*dot, contract off.
template <int N, int NS>
__global__ __launch_bounds__(256) void ball_query_kernel(
    const float* __restrict__ xyz, const float* __restrict__ new_xyz,
    int* __restrict__ nidx, int S, float r2) {
#pragma clang fp contract(off)
  const int wv = threadIdx.x >> 6;
  const int lane = threadIdx.x & 63;
  const int b = blockIdx.y;
  const int s = blockIdx.x * 4 + wv;
  __shared__ int s_idx[4][NS];
  const float* base = xyz + (size_t)b * N * 3;

  float cx = new_xyz[((size_t)(b * S + s)) * 3 + 0];
  float cy = new_xyz[((size_t)(b * S + s)) * 3 + 1];
  float cz = new_xyz[((size_t)(b * S + s)) * 3 + 2];
  float sc = (cx * cx + cy * cy) + cz * cz;

  int found = 0;
  for (int i0 = 0; i0 < N && found < NS; i0 += 64) {  // N % 64 == 0 always
    int i = i0 + lane;
    float x = base[i * 3 + 0];
    float y = base[i * 3 + 1];
    float z = base[i * 3 + 2];
    float sx = (x * x + y * y) + z * z;
    float dt = (cx * x + cy * y) + cz * z;
    float d2 = (sc + sx) - 2.0f * dt;
    bool inb = d2 < r2;
    unsigned long long m = __ballot(inb);
    if (inb) {
      int pos = found + __popcll(m & ((1ull << lane) - 1));
      if (pos < NS) s_idx[wv][pos] = i;
    }
    found += __popcll(m);
  }
  __syncthreads();
  int fcnt = found < NS ? found : NS;
  int first = s_idx[wv][0];
  int* outp = nidx + ((size_t)(b * S + s)) * NS;
  for (int j = lane; j < NS; j += 64) outp[j] = (j < fcnt) ? s_idx[wv][j] : first;
}

// --------------------------- fused group MLP -------------------------------
// act[R][CMAXP] in LDS holds activations in-place across the 3 layers.
// Thread grid RG x CG; each thread owns RPT rows x CPT cols; W streamed from
// L1/L2 (each W element feeds RPT FMAs).
template <int R, int RG, int CG, int CMAXP, int CIN, int COUT>
__device__ __forceinline__ void mlp_layer(float* act, const float* __restrict__ w,
                                          const float* __restrict__ bias, int tid) {
  constexpr int RPT = R / RG;
  constexpr int CPT = COUT / CG;
  static_assert(RG * CG == 256, "thread grid");
  const int rg = tid / CG;
  const int cg = tid % CG;

  float acc[RPT][CPT];
#pragma unroll
  for (int rr = 0; rr < RPT; ++rr)
#pragma unroll
    for (int cc = 0; cc < CPT; ++cc) acc[rr][cc] = 0.f;

  constexpr int K4 = (CIN / 4) * 4;
  for (int k = 0; k < K4; k += 4) {
    float4 a[RPT];
#pragma unroll
    for (int rr = 0; rr < RPT; ++rr)
      a[rr] = *(const float4*)(&act[(rg * RPT + rr) * CMAXP + k]);
    float wvv[4][CPT];
#pragma unroll
    for (int kk = 0; kk < 4; ++kk)
#pragma unroll
      for (int cc = 0; cc < CPT; ++cc)
        wvv[kk][cc] = w[(size_t)(k + kk) * COUT + cg + cc * CG];
#pragma unroll
    for (int rr = 0; rr < RPT; ++rr) {
      float4 av = a[rr];
#pragma unroll
      for (int cc = 0; cc < CPT; ++cc) {
        acc[rr][cc] += av.x * wvv[0][cc];
        acc[rr][cc] += av.y * wvv[1][cc];
        acc[rr][cc] += av.z * wvv[2][cc];
        acc[rr][cc] += av.w * wvv[3][cc];
      }
    }
  }
#pragma unroll 1
  for (int k = K4; k < CIN; ++k) {
    float wvv[CPT];
#pragma unroll
    for (int cc = 0; cc < CPT; ++cc) wvv[cc] = w[(size_t)k * COUT + cg + cc * CG];
#pragma unroll
    for (int rr = 0; rr < RPT; ++rr) {
      float av = act[(rg * RPT + rr) * CMAXP + k];
#pragma unroll
      for (int cc = 0; cc < CPT; ++cc) acc[rr][cc] += av * wvv[cc];
    }
  }
  __syncthreads();  // all reads of act done before in-place overwrite
#pragma unroll
  for (int rr = 0; rr < RPT; ++rr)
#pragma unroll
    for (int cc = 0; cc < CPT; ++cc) {
      int co = cg + cc * CG;
      float v = acc[rr][cc] + bias[co];
      act[(rg * RPT + rr) * CMAXP + co] = fmaxf(v, 0.f);
    }
  __syncthreads();
}

template <int NS, int G, int CPREV, int CO0, int CO1, int CO2, int RG, int CG, int CMAXP>
__global__ __launch_bounds__(256) void group_mlp_kernel(
    const float* __restrict__ xyz, const float* __restrict__ new_xyz,
    const float* __restrict__ feats, const int* __restrict__ nidx,
    const float* __restrict__ w0, const float* __restrict__ b0,
    const float* __restrict__ w1, const float* __restrict__ b1,
    const float* __restrict__ w2, const float* __restrict__ b2,
    float* __restrict__ out, int N, int S, float radius) {
  constexpr int R = NS * G;
  constexpr int CIN = 3 + CPREV;
  __shared__ __align__(16) float act[R * CMAXP];
  const int tid = threadIdx.x;
  const int b = blockIdx.y;
  const int s0 = blockIdx.x * G;

  // stage inputs: rel xyz (exact sub + div by radius) and gathered feats
  for (int i = tid; i < R * CIN; i += 256) {
    int row = i / CIN;
    int ch = i - row * CIN;
    int g = row / NS;
    int j = row - g * NS;
    int sidx = s0 + g;
    int n = nidx[((size_t)(b * S + sidx)) * NS + j];
    float v;
    if constexpr (CPREV == 0) {
      v = (xyz[((size_t)(b * N + n)) * 3 + ch] -
           new_xyz[((size_t)(b * S + sidx)) * 3 + ch]) /
          radius;
    } else {
      if (ch < 3) {
        v = (xyz[((size_t)(b * N + n)) * 3 + ch] -
             new_xyz[((size_t)(b * S + sidx)) * 3 + ch]) /
            radius;
      } else {
        v = feats[((size_t)(b * N + n)) * CPREV + (ch - 3)];
      }
    }
    act[row * CMAXP + ch] = v;
  }
  __syncthreads();

  mlp_layer<R, RG, CG, CMAXP, CIN, CO0>(act, w0, b0, tid);
  mlp_layer<R, RG, CG, CMAXP, CO0, CO1>(act, w1, b1, tid);
  mlp_layer<R, RG, CG, CMAXP, CO1, CO2>(act, w2, b2, tid);

  // maxpool over NS neighbors per group
  for (int i = tid; i < G * CO2; i += 256) {
    int g = i / CO2;
    int co = i - g * CO2;
    float m = act[(g * NS) * CMAXP + co];
    for (int j = 1; j < NS; ++j) m = fmaxf(m, act[(g * NS + j) * CMAXP + co]);
    out[((size_t)(b * S + s0 + g)) * CO2 + co] = m;
  }
}

// ---------------------------------------------------------------------------
extern "C" void kernel_launch(void* const* d_in, const int* in_sizes, int n_in,
                              void* d_out, int out_size, void* d_ws, size_t ws_size,
                              hipStream_t stream) {
  (void)in_sizes; (void)n_in; (void)out_size; (void)ws_size;
  const float* pc = (const float*)d_in[0];
  const float* W[4][3];
  const float* Bb[4][3];
  for (int s = 0; s < 4; ++s)
    for (int l = 0; l < 3; ++l) {
      W[s][l] = (const float*)d_in[1 + s * 6 + l * 2];
      Bb[s][l] = (const float*)d_in[2 + s * 6 + l * 2];
    }

  // workspace layout (bytes): fidx 32KB | nidx 2MB | xyzA 96KB | xyzB 96KB |
  // featA 4MB | featB 4MB   (total ~10.2 MB)
  char* wsp = (char*)d_ws;
  int* fidx = (int*)wsp;
  int* nidx = (int*)(wsp + (32 << 10));
  float* xyzA = (float*)(wsp + (32 << 10) + (2 << 20));
  float* xyzB = xyzA + B_SZ * 2048 * 3;
  float* featA = xyzB + B_SZ * 2048 * 3;
  float* featB = featA + B_SZ * 2048 * 128;
  float* oxyz = (float*)d_out;           // [4,256,3]
  float* ofeat = oxyz + B_SZ * 256 * 3;  // [4,256,512]

  // ---------------- Stage 1: N=16384 -> S=2048, r=0.2, ns=64, 3->64->64->128
  hipLaunchKernelGGL((fps_kernel<16384, 2048, 1024, false>), dim3(B_SZ), dim3(1024), 0, stream,
                     pc, fidx);
  hipLaunchKernelGGL(gather_xyz_kernel, dim3(32, B_SZ), dim3(64), 0, stream,
                     pc, fidx, xyzA, 16384, 2048);
  hipLaunchKernelGGL((ball_query_kernel<16384, 64>), dim3(512, B_SZ), dim3(256), 0, stream,
                     pc, xyzA, nidx, 2048, (float)(0.2 * 0.2));
  hipLaunchKernelGGL((group_mlp_kernel<64, 1, 0, 64, 64, 128, 8, 32, 128>),
                     dim3(2048, B_SZ), dim3(256), 0, stream,
                     pc, xyzA, (const float*)nullptr, nidx,
                     W[0][0], Bb[0][0], W[0][1], Bb[0][1], W[0][2], Bb[0][2],
                     featA, 16384, 2048, 0.2f);

  // ---------------- Stage 2: N=2048 -> S=1024, r=0.4, ns=32, 131->128->128->256
  hipLaunchKernelGGL((fps_kernel<2048, 1024, 512, true>), dim3(B_SZ), dim3(512), 0, stream,
                     xyzA, fidx);
  hipLaunchKernelGGL(gather_xyz_kernel, dim3(16, B_SZ), dim3(64), 0, stream,
                     xyzA, fidx, xyzB, 2048, 1024);
  hipLaunchKernelGGL((ball_query_kernel<2048, 32>), dim3(256, B_SZ), dim3(256), 0, stream,
                     xyzA, xyzB, nidx, 1024, (float)(0.4 * 0.4));
  hipLaunchKernelGGL((group_mlp_kernel<32, 1, 128, 128, 128, 256, 4, 64, 256>),
                     dim3(1024, B_SZ), dim3(256), 0, stream,
                     xyzA, xyzB, featA, nidx,
                     W[1][0], Bb[1][0], W[1][1], Bb[1][1], W[1][2], Bb[1][2],
                     featB, 2048, 1024, 0.4f);

  // ---------------- Stage 3: N=1024 -> S=512, r=0.6, ns=16, 259->256->256->512
  hipLaunchKernelGGL((fps_kernel<1024, 512, 512, true>), dim3(B_SZ), dim3(512), 0, stream,
                     xyzB, fidx);
  hipLaunchKernelGGL(gather_xyz_kernel, dim3(8, B_SZ), dim3(64), 0, stream,
                     xyzB, fidx, xyzA, 1024, 512);
  hipLaunchKernelGGL((ball_query_kernel<1024, 16>), dim3(128, B_SZ), dim3(256), 0, stream,
                     xyzB, xyzA, nidx, 512, (float)(0.6 * 0.6));
  hipLaunchKernelGGL((group_mlp_kernel<16, 1, 256, 256, 256, 512, 2, 128, 512>),
                     dim3(512, B_SZ), dim3(256), 0, stream,
                     xyzB, xyzA, featB, nidx,
                     W[2][0], Bb[2][0], W[2][1], Bb[2][1], W[2][2], Bb[2][2],
                     featA, 1024, 512, 0.6f);

  // ---------------- Stage 4: N=512 -> S=256, r=1.2, ns=8, 515->512->512->512
  hipLaunchKernelGGL((fps_kernel<512, 256, 256, true>), dim3(B_SZ), dim3(256), 0, stream,
                     xyzA, fidx);
  hipLaunchKernelGGL(gather_xyz_kernel, dim3(4, B_SZ), dim3(64), 0, stream,
                     xyzA, fidx, oxyz, 512, 256);
  hipLaunchKernelGGL((ball_query_kernel<512, 8>), dim3(64, B_SZ), dim3(256), 0, stream,
                     xyzA, oxyz, nidx, 256, (float)(1.2 * 1.2));
  hipLaunchKernelGGL((group_mlp_kernel<8, 2, 512, 512, 512, 512, 2, 128, 516>),
                     dim3(128, B_SZ), dim3(256), 0, stream,
                     xyzA, oxyz, featA, nidx,
                     W[3][0], Bb[3][0], W[3][1], Bb[3][1], W[3][2], Bb[3][2],
                     ofeat, 512, 256, 1.2f);
}